// Round 18
// baseline (2674.994 us; speedup 1.0000x reference)
//
#include <hip/hip_runtime.h>
#include <hip/hip_fp16.h>

#define B_TOT 32768
#define D1 4096
#define D2 2048
#define D3 1024
#define NCLS 19

typedef _Float16 f16;
typedef __attribute__((ext_vector_type(8))) _Float16 f16x8;
typedef __attribute__((ext_vector_type(4))) float f32x4;

// ---------------- helpers ----------------

__device__ __forceinline__ void gl_lds16(void* ldsDst, const void* gSrc) {
  __builtin_amdgcn_global_load_lds(
      (__attribute__((address_space(1))) void*)(void*)(gSrc),
      (__attribute__((address_space(3))) void*)(ldsDst),
      16, 0, 0);
}

__device__ __forceinline__ float gelu_f(float x) {
  return 0.5f * x * (1.0f + erff(x * 0.70710678118654752f));
}

// v ~= (float)h + (float)l * (1/4096)
__device__ __forceinline__ void mk_pair(float v, f16& h, f16& l) {
  f16 hh = (f16)v;
  h = hh;
  l = (f16)((v - (float)hh) * 4096.0f);
}

#define FENCE asm volatile("" ::: "memory")
#define BARRIER { FENCE; __builtin_amdgcn_s_barrier(); FENCE; }
#define WAITV6 asm volatile("s_waitcnt vmcnt(6)" ::: "memory")
#define WAITV5 asm volatile("s_waitcnt vmcnt(5)" ::: "memory")
#define WAITV4 asm volatile("s_waitcnt vmcnt(4)" ::: "memory")
#define WAITV3 asm volatile("s_waitcnt vmcnt(3)" ::: "memory")
#define WAITV2 asm volatile("s_waitcnt vmcnt(2)" ::: "memory")
#define WAITV0 asm volatile("s_waitcnt vmcnt(0)" ::: "memory")

// ---------------- prep kernels ----------------

// Transpose W -> Th [N][K] = gam[k]*W[k][n] (gam==nullptr -> 1), f16.
// If up != nullptr, ALSO emits per-k-block u/v partials (merged uv_part).
__global__ void transpose_pair_kernel(const float* __restrict__ W,
                                      const float* __restrict__ gam,
                                      const float* __restrict__ bet,
                                      f16* __restrict__ Th, f16* __restrict__ Tl,
                                      float* __restrict__ up, float* __restrict__ vp,
                                      int K, int N) {
  __shared__ float t[64][65];
  __shared__ float su4[4][64], sv4[4][64];
  int k0 = blockIdx.y * 64, n0 = blockIdx.x * 64;
  int tx = threadIdx.x & 63, ty = threadIdx.x >> 6;
#pragma unroll
  for (int i = 0; i < 16; ++i) {
    int kl = ty + i * 4;
    int kk = k0 + kl;
    if (kk < K) t[kl][tx] = W[(size_t)kk * N + n0 + tx];   // raw W
  }
  __syncthreads();
  if (up) {
    float su = 0.f, sv = 0.f;
#pragma unroll
    for (int i = 0; i < 16; ++i) {
      int kl = ty + i * 4;
      int kk = k0 + kl;
      if (kk < K) {
        float w = t[kl][tx];
        su += gam[kk] * w;
        sv += bet[kk] * w;
      }
    }
    su4[ty][tx] = su; sv4[ty][tx] = sv;
  }
  __syncthreads();
#pragma unroll
  for (int i = 0; i < 16; ++i) {
    int nl = ty + i * 4;
    int kk = k0 + tx;
    if (kk < K) {
      float s = gam ? gam[kk] : 1.0f;
      float v = s * t[tx][nl];
      f16 h, l; mk_pair(v, h, l);
      size_t o = (size_t)(n0 + nl) * K + kk;
      Th[o] = h;
      if (Tl) Tl[o] = l;
    }
  }
  if (up && ty == 0) {
    float su = su4[0][tx] + su4[1][tx] + su4[2][tx] + su4[3][tx];
    float sv = sv4[0][tx] + sv4[1][tx] + sv4[2][tx] + sv4[3][tx];
    up[(size_t)blockIdx.y * N + n0 + tx] = su;
    vp[(size_t)blockIdx.y * N + n0 + tx] = sv;
  }
}

// w4g[k][c] = gam3[k] * W4[k][c]
__global__ void w4g_kernel(const float* __restrict__ W4, const float* __restrict__ gam,
                           float* __restrict__ w4g) {
  int i = blockIdx.x * 256 + threadIdx.x;
  if (i < D3 * NCLS) w4g[i] = gam[i / NCLS] * W4[i];
}

// u4[c] = sum_k gam3[k]*W4[k][c]; v4[c] = sum_k bet3[k]*W4[k][c]
__global__ void uv4_kernel(const float* __restrict__ W4, const float* __restrict__ gam,
                           const float* __restrict__ bet,
                           float* __restrict__ u4, float* __restrict__ v4) {
  int c = threadIdx.x;
  if (c >= NCLS) return;
  float su = 0.f, sv = 0.f;
  for (int k = 0; k < D3; ++k) {
    float w = W4[(size_t)k * NCLS + c];
    su += gam[k] * w;
    sv += bet[k] * w;
  }
  u4[c] = su; v4[c] = sv;
}

__global__ void uv_reduce_kernel(const float* __restrict__ up, const float* __restrict__ vp,
                                 float* __restrict__ u, float* __restrict__ v,
                                 int N, int nc) {
  int n = blockIdx.x * 256 + threadIdx.x;
  if (n >= N) return;
  float su = 0.f, sv = 0.f;
  for (int c = 0; c < nc; ++c) {
    su += up[(size_t)c * N + n];
    sv += vp[(size_t)c * N + n];
  }
  u[n] = su; v[n] = sv;
}

__global__ void pair_kernel(const float* __restrict__ x, f16* __restrict__ h, int n) {
  int i = blockIdx.x * 256 + threadIdx.x;
  if (i < n) h[i] = (f16)x[i];
}

// ---------------- layer-1 GEMM (K=32 single tile + one-hot gathers), f16 x f16 ----------------

__global__ __launch_bounds__(256, 4)
void gemm1(const f16* __restrict__ Ah, const f16* __restrict__ Bh,
           const float* __restrict__ bias,
           const int* __restrict__ c0, const int* __restrict__ c1,
           const int* __restrict__ c2, const float* __restrict__ W1raw,
           float* __restrict__ part_s, float* __restrict__ part_q, int nparts,
           f16* __restrict__ Gh) {
  constexpr int K = 32, N = D1;
  __shared__ __align__(16) f16 AhS[128 * 32];
  __shared__ __align__(16) f16 BhS[128 * 32];

  const int tid = threadIdx.x;
  const int wave = tid >> 6, lane = tid & 63;
  const int wr = wave >> 1, wc = wave & 1;
  const int lq = lane >> 4, lr = lane & 15;

  const int gx = gridDim.x;
  const int nwg = gx * gridDim.y;
  const int flat = blockIdx.y * gx + blockIdx.x;
  const int cpx = nwg >> 3;
  const int swz = (flat & 7) * cpx + (flat >> 3);
  const int bx = swz % gx, by = swz / gx;
  const int m0 = by * 128, n0 = bx * 128;

#pragma unroll
  for (int i = 0; i < 2; ++i) {
    int idx = i * 256 + tid;
    int rr = idx >> 2, kq = idx & 3;
    int kqg = kq ^ ((rr >> 1) & 3);
    gl_lds16(&AhS[idx * 8], Ah + (size_t)(m0 + rr) * K + kqg * 8);
    gl_lds16(&BhS[idx * 8], Bh + (size_t)(n0 + rr) * K + kqg * 8);
  }
  WAITV0;
  BARRIER;

  f32x4 acc0[4][4];
  const f32x4 vz = {0.f, 0.f, 0.f, 0.f};
#pragma unroll
  for (int a = 0; a < 4; ++a)
#pragma unroll
    for (int b = 0; b < 4; ++b) acc0[a][b] = vz;

  f16x8 af[4], bf[4];
#pragma unroll
  for (int mf = 0; mf < 4; ++mf) {
    int row = wr * 64 + mf * 16 + lr;
    int ca = lq ^ ((row >> 1) & 3);
    af[mf] = *(const f16x8*)(&AhS[row * 32 + ca * 8]);
  }
#pragma unroll
  for (int nf = 0; nf < 4; ++nf) {
    int col = wc * 64 + nf * 16 + lr;
    int cb = lq ^ ((col >> 1) & 3);
    bf[nf] = *(const f16x8*)(&BhS[col * 32 + cb * 8]);
  }
#pragma unroll
  for (int mf = 0; mf < 4; ++mf)
#pragma unroll
    for (int nf = 0; nf < 4; ++nf)
      acc0[mf][nf] = __builtin_amdgcn_mfma_f32_16x16x32_f16(af[mf], bf[nf], acc0[mf][nf], 0, 0, 0);

  const int pidx = bx * 2 + wc;
#pragma unroll
  for (int mf = 0; mf < 4; ++mf) {
#pragma unroll
    for (int j = 0; j < 4; ++j) {
      const int row = m0 + wr * 64 + mf * 16 + lq * 4 + j;
      const int g0 = 32 + c0[row], g1i = 96 + c1[row], g2i = 224 + c2[row];
      float rowsum = 0.f, rowsq = 0.f;
#pragma unroll
      for (int nf = 0; nf < 4; ++nf) {
        const int col = n0 + wc * 64 + nf * 16 + lr;
        float pre = acc0[mf][nf][j] + bias[col]
                  + W1raw[(size_t)g0 * D1 + col]
                  + W1raw[(size_t)g1i * D1 + col]
                  + W1raw[(size_t)g2i * D1 + col];
        float g = gelu_f(pre);
        Gh[(size_t)row * N + col] = (f16)g;
        rowsum += g; rowsq += g * g;
      }
#pragma unroll
      for (int off = 1; off < 16; off <<= 1) {
        rowsum += __shfl_xor(rowsum, off);
        rowsq  += __shfl_xor(rowsq, off);
      }
      if (lr == 0) {
        part_s[(size_t)row * nparts + pidx] = rowsum;
        part_q[(size_t)row * nparts + pidx] = rowsq;
      }
    }
  }
}

// ---------------- pipelined f16 GEMM (layers 2/3) — round-7 proven schedule ----------------
// r18: BOTH layers use WM=2 (BM=128): LDS ~49 KB -> 3 blocks/CU (24 waves =
// 75% occupancy); __launch_bounds__(512,6) caps VGPR at 85 so the allocator
// honors 6 waves/EU. Occupancy is the stall-filler now that the 1-MFMA
// formulation makes per-phase MFMA tiny (m114 cross-block overlap).
// Loads/tile LD = (WM/2)*(1+ALO) + 1 + BLO; entry wait vmcnt(LD).
// FUSE=true (L3): epilogue emits per-(row, col-block) 19-wide partial logit
// dots (LN3 affine fold) and skips the G3 store entirely.

template <int WM, bool FUSE, bool BLO, bool ALO>
__global__ __launch_bounds__(512, (WM == 2 && !BLO && !ALO) ? 6 : 2)
void gemm_ln(const f16* __restrict__ Ah, const f16* __restrict__ Al,
             const f16* __restrict__ Bh, const f16* __restrict__ Bl,
             int K, int N,
             const float* __restrict__ bias,
             const float* __restrict__ uvec, const float* __restrict__ vvec,
             const float* __restrict__ ps_in, const float* __restrict__ pq_in,
             int np_, float invN,
             float* __restrict__ part_s, float* __restrict__ part_q, int nparts,
             f16* __restrict__ Gh, f16* __restrict__ Gl,
             const float* __restrict__ w4g, float* __restrict__ praw) {
  constexpr int BM = WM * 64;
  constexpr bool USE1 = ALO || BLO;
  __shared__ __align__(16) f16 AhS[3 * BM * 32];
  __shared__ __align__(16) f16 AlS[ALO ? 3 * BM * 32 : 16];
  __shared__ __align__(16) f16 BhS[3 * 128 * 32];
  __shared__ __align__(16) f16 BlS[BLO ? 3 * 128 * 32 : 16];
  __shared__ float mS[BM], rsS[BM];

  const int tid = threadIdx.x;
  const int wave = tid >> 6, lane = tid & 63;
  const int wr = wave >> 1, wc = wave & 1;
  const int lq = lane >> 4, lr = lane & 15;

  const int gx = gridDim.x;
  const int nwg = gx * gridDim.y;
  const int flat = blockIdx.y * gx + blockIdx.x;
  const int cpx = nwg >> 3;
  const int swz = (flat & 7) * cpx + (flat >> 3);
  const int bx = swz % gx, by = swz / gx;
  const int m0 = by * BM, n0 = bx * 128;

  // ---- in-kernel LN stats for this block's rows ----
  for (int r = tid; r < BM; r += 512) {
    const float* pr = ps_in + (size_t)(m0 + r) * np_;
    const float* qr = pq_in + (size_t)(m0 + r) * np_;
    float s = 0.f, q = 0.f;
    for (int pp = 0; pp < np_; pp += 4) {
      float4 a = *(const float4*)(pr + pp);
      float4 b = *(const float4*)(qr + pp);
      s += a.x + a.y + a.z + a.w;
      q += b.x + b.y + b.z + b.w;
    }
    float mean = s * invN;
    mS[r] = mean;
    rsS[r] = 1.0f / sqrtf(q * invN - mean * mean + 1e-5f);
  }

  f32x4 acc0[WM][4], acc1[USE1 ? WM : 1][4];
  const f32x4 vz = {0.f, 0.f, 0.f, 0.f};
#pragma unroll
  for (int a = 0; a < WM; ++a)
#pragma unroll
    for (int b = 0; b < 4; ++b) {
      acc0[a][b] = vz;
      if constexpr (USE1) acc1[a][b] = vz;
    }

  const int nkt = K >> 5;

  auto stage0 = [&](int b, int kt_) {
    const int k0_ = kt_ << 5;
#pragma unroll
    for (int r = 0; r < WM / 2; ++r) {
      int idx = r * 512 + tid, rr = idx >> 2, kq = idx & 3;
      int kqg = kq ^ ((rr >> 1) & 3);
      gl_lds16(&AhS[b * (BM * 32) + idx * 8], Ah + (size_t)(m0 + rr) * K + k0_ + kqg * 8);
    }
    { int rr = tid >> 2, kq = tid & 3, kqg = kq ^ ((rr >> 1) & 3);
      gl_lds16(&BhS[b * (128 * 32) + tid * 8], Bh + (size_t)(n0 + rr) * K + k0_ + kqg * 8); }
  };
  auto stage1 = [&](int b, int kt_) {
    const int k0_ = kt_ << 5;
    if constexpr (ALO) {
#pragma unroll
      for (int r = 0; r < WM / 2; ++r) {
        int idx = r * 512 + tid, rr = idx >> 2, kq = idx & 3;
        int kqg = kq ^ ((rr >> 1) & 3);
        gl_lds16(&AlS[b * (BM * 32) + idx * 8], Al + (size_t)(m0 + rr) * K + k0_ + kqg * 8);
      }
    }
    if constexpr (BLO) {
      int rr = tid >> 2, kq = tid & 3, kqg = kq ^ ((rr >> 1) & 3);
      gl_lds16(&BlS[b * (128 * 32) + tid * 8], Bl + (size_t)(n0 + rr) * K + k0_ + kqg * 8);
    }
  };

  // prologue: tiles 0 and 1 in flight
  stage0(0, 0);
  if constexpr (USE1) stage1(0, 0);
  if (nkt > 1) { stage0(1, 1); if constexpr (USE1) stage1(1, 1); }

  for (int t = 0; t < nkt; ++t) {
    const int cb = t % 3;              // compute buffer
    const int sb = (t + 2) % 3;        // stage target (== buffer of t-1)
    if (t + 1 < nkt) {
      constexpr int LD = (WM / 2) * (1 + (ALO ? 1 : 0)) + 1 + (BLO ? 1 : 0);
      if constexpr (LD >= 6) { WAITV6; }
      else if constexpr (LD == 5) { WAITV5; }
      else if constexpr (LD == 4) { WAITV4; }
      else if constexpr (LD == 3) { WAITV3; }
      else { WAITV2; }
    } else {
      WAITV0;
    }
    BARRIER;

    const bool pf = (t + 2 < nkt);

    f16x8 bf[4], blf[4];
#pragma unroll
    for (int ph = 0; ph < WM / 2; ++ph) {
      const int mfA = ph * 2, mfB = ph * 2 + 1;
      f16x8 aA, aAl, aB, aBl;
      {
        int rowA = wr * (WM * 16) + mfA * 16 + lr;
        int caA = lq ^ ((rowA >> 1) & 3);
        aA = *(const f16x8*)(&AhS[cb * (BM * 32) + rowA * 32 + caA * 8]);
        if constexpr (ALO) aAl = *(const f16x8*)(&AlS[cb * (BM * 32) + rowA * 32 + caA * 8]);
        int rowB = wr * (WM * 16) + mfB * 16 + lr;
        int caB = lq ^ ((rowB >> 1) & 3);
        aB = *(const f16x8*)(&AhS[cb * (BM * 32) + rowB * 32 + caB * 8]);
        if constexpr (ALO) aBl = *(const f16x8*)(&AlS[cb * (BM * 32) + rowB * 32 + caB * 8]);
      }
      if (ph == 0) {
#pragma unroll
        for (int nf = 0; nf < 4; ++nf) {
          int col = wc * 64 + nf * 16 + lr;
          int cc = lq ^ ((col >> 1) & 3);
          bf[nf] = *(const f16x8*)(&BhS[cb * (128 * 32) + col * 32 + cc * 8]);
          if constexpr (BLO)
            blf[nf] = *(const f16x8*)(&BlS[cb * (128 * 32) + col * 32 + cc * 8]);
        }
      }
      if (pf) {
        if (ph == 0) { stage0(sb, t + 2); if (WM == 2) { if constexpr (USE1) stage1(sb, t + 2); } }
        if (ph == 1) { if constexpr (USE1) stage1(sb, t + 2); }
      }
      BARRIER;
      __builtin_amdgcn_s_setprio(1);
#pragma unroll
      for (int nf = 0; nf < 4; ++nf) {
        acc0[mfA][nf] = __builtin_amdgcn_mfma_f32_16x16x32_f16(aA, bf[nf], acc0[mfA][nf], 0, 0, 0);
        if constexpr (BLO)
          acc1[mfA][nf] = __builtin_amdgcn_mfma_f32_16x16x32_f16(aA, blf[nf], acc1[mfA][nf], 0, 0, 0);
        if constexpr (ALO)
          acc1[mfA][nf] = __builtin_amdgcn_mfma_f32_16x16x32_f16(aAl, bf[nf], acc1[mfA][nf], 0, 0, 0);
      }
#pragma unroll
      for (int nf = 0; nf < 4; ++nf) {
        acc0[mfB][nf] = __builtin_amdgcn_mfma_f32_16x16x32_f16(aB, bf[nf], acc0[mfB][nf], 0, 0, 0);
        if constexpr (BLO)
          acc1[mfB][nf] = __builtin_amdgcn_mfma_f32_16x16x32_f16(aB, blf[nf], acc1[mfB][nf], 0, 0, 0);
        if constexpr (ALO)
          acc1[mfB][nf] = __builtin_amdgcn_mfma_f32_16x16x32_f16(aBl, bf[nf], acc1[mfB][nf], 0, 0, 0);
      }
      __builtin_amdgcn_s_setprio(0);
    }
  }

  // ---- epilogue: LN fold + gelu + (store | fused logit partials) ----
  const int pidx = bx * 2 + wc;
#pragma unroll
  for (int mf = 0; mf < WM; ++mf) {
#pragma unroll
    for (int j = 0; j < 4; ++j) {
      const int rl = wr * (WM * 16) + mf * 16 + lq * 4 + j;
      const int row = m0 + rl;
      const float mA = mS[rl], rsA = rsS[rl];
      float gval[4];
      float rowsum = 0.f, rowsq = 0.f;
#pragma unroll
      for (int nf = 0; nf < 4; ++nf) {
        const int col = n0 + wc * 64 + nf * 16 + lr;
        float val = acc0[mf][nf][j];
        if constexpr (USE1) val += acc1[mf][nf][j] * (1.0f / 4096.0f);
        float pre = rsA * val - rsA * mA * uvec[col] + vvec[col] + bias[col];
        float g = gelu_f(pre);
        gval[nf] = g;
        if constexpr (!FUSE) {
          f16 h, l; mk_pair(g, h, l);
          size_t o = (size_t)row * N + col;
          Gh[o] = h;
          if (Gl) Gl[o] = l;
        }
        rowsum += g; rowsq += g * g;
      }
      float lacc[NCLS];
      if constexpr (FUSE) {
#pragma unroll
        for (int c = 0; c < NCLS; ++c) lacc[c] = 0.f;
#pragma unroll
        for (int nf = 0; nf < 4; ++nf) {
          const int col = n0 + wc * 64 + nf * 16 + lr;
          const float* wrow = w4g + (size_t)col * NCLS;
          const float gv = gval[nf];
#pragma unroll
          for (int c = 0; c < NCLS; ++c) lacc[c] += gv * wrow[c];
        }
#pragma unroll
        for (int off = 1; off < 16; off <<= 1) {
#pragma unroll
          for (int c = 0; c < NCLS; ++c) lacc[c] += __shfl_xor(lacc[c], off);
        }
      }
#pragma unroll
      for (int off = 1; off < 16; off <<= 1) {
        rowsum += __shfl_xor(rowsum, off);
        rowsq  += __shfl_xor(rowsq, off);
      }
      if (lr == 0) {
        part_s[(size_t)row * nparts + pidx] = rowsum;
        part_q[(size_t)row * nparts + pidx] = rowsq;
        if constexpr (FUSE) {
          float* pw = praw + ((size_t)row * 16 + pidx) * NCLS;
#pragma unroll
          for (int c = 0; c < NCLS; ++c) pw[c] = lacc[c];
        }
      }
    }
  }
}

// ---------------- head: combine partial dots + LN3 affine + mask + softmax + argmax ----

__global__ __launch_bounds__(256)
void head_kernel(const float* __restrict__ ps3, const float* __restrict__ pq3,
                 const float* __restrict__ praw,
                 const float* __restrict__ u4, const float* __restrict__ v4,
                 const float* __restrict__ b4,
                 const int* __restrict__ pid, const float* __restrict__ amask,
                 float* __restrict__ out_ml, float* __restrict__ out_p,
                 float* __restrict__ out_pred, int rows) {
  const int wave = threadIdx.x >> 6, lane = threadIdx.x & 63;
  const int r = blockIdx.x * 4 + wave;
  if (r >= rows) return;
  const int lp = lane & 15;
  float s = ps3[(size_t)r * 16 + lp];
  float q = pq3[(size_t)r * 16 + lp];
  float acc[NCLS];
  {
    const float* pr = praw + ((size_t)r * 16 + lp) * NCLS;
#pragma unroll
    for (int c = 0; c < NCLS; ++c) acc[c] = pr[c];
  }
#pragma unroll
  for (int off = 1; off < 16; off <<= 1) {
    s += __shfl_xor(s, off);
    q += __shfl_xor(q, off);
#pragma unroll
    for (int c = 0; c < NCLS; ++c) acc[c] += __shfl_xor(acc[c], off);
  }
  const float invN3 = 1.0f / (float)D3;
  const float m = s * invN3;
  const float rs = 1.0f / sqrtf(q * invN3 - m * m + 1e-5f);

  const int p = pid[r];
  float ml[NCLS], mx = -3.4e38f;
#pragma unroll
  for (int c = 0; c < NCLS; ++c) {
    ml[c] = rs * acc[c] - rs * m * u4[c] + v4[c] + b4[c] + amask[(size_t)p * NCLS + c];
    mx = fmaxf(mx, ml[c]);
  }
  float ex[NCLS], ssum = 0.f;
#pragma unroll
  for (int c = 0; c < NCLS; ++c) { ex[c] = expf(ml[c] - mx); ssum += ex[c]; }
  const float inv = 1.0f / ssum;
  float pr2[NCLS];
#pragma unroll
  for (int c = 0; c < NCLS; ++c) pr2[c] = ex[c] * inv;
  int best = 0; float bp = pr2[0];
#pragma unroll
  for (int c = 1; c < NCLS; ++c) { if (pr2[c] > bp) { bp = pr2[c]; best = c; } }
  if (lane < NCLS) {
    out_ml[(size_t)r * NCLS + lane] = ml[lane];
    out_p [(size_t)r * NCLS + lane] = pr2[lane];
  }
  if (lane == 0) out_pred[r] = (float)best;
}

// ---------------- host ----------------

extern "C" void kernel_launch(void* const* d_in, const int* in_sizes, int n_in,
                              void* d_out, int out_size, void* d_ws, size_t ws_size,
                              hipStream_t stream) {
  const float* numeric = (const float*)d_in[0];
  const int*   cat0 = (const int*)d_in[1];
  const int*   cat1 = (const int*)d_in[2];
  const int*   cat2 = (const int*)d_in[3];
  const int*   pid  = (const int*)d_in[4];
  const float* amask= (const float*)d_in[5];
  const float* W1 = (const float*)d_in[6];
  const float* b1 = (const float*)d_in[7];
  const float* g1v= (const float*)d_in[8];
  const float* be1= (const float*)d_in[9];
  const float* W2 = (const float*)d_in[10];
  const float* b2 = (const float*)d_in[11];
  const float* g2v= (const float*)d_in[12];
  const float* be2= (const float*)d_in[13];
  const float* W3 = (const float*)d_in[14];
  const float* b3 = (const float*)d_in[15];
  const float* g3v= (const float*)d_in[16];
  const float* be3= (const float*)d_in[17];
  const float* W4 = (const float*)d_in[18];
  const float* b4 = (const float*)d_in[19];
  (void)in_sizes; (void)n_in; (void)out_size;

  char* p = (char*)d_ws;
  auto alloc = [&](size_t bytes) -> char* {
    char* r = p;
    p += (bytes + 255) & ~(size_t)255;
    return r;
  };

  // fixed workspace
  f16* W1t_h = (f16*)alloc((size_t)D1 * 32 * 2);
  f16* W2t_h = (f16*)alloc((size_t)D2 * D1 * 2);
  f16* W3t_h = (f16*)alloc((size_t)D3 * D2 * 2);
  f16* An_h  = (f16*)alloc((size_t)B_TOT * 32 * 2);
  float* u2  = (float*)alloc((size_t)D2 * 4);
  float* v2  = (float*)alloc((size_t)D2 * 4);
  float* u3  = (float*)alloc((size_t)D3 * 4);
  float* v3  = (float*)alloc((size_t)D3 * 4);
  float* w4g = (float*)alloc((size_t)D3 * NCLS * 4);
  float* u4  = (float*)alloc((size_t)NCLS * 4);
  float* v4  = (float*)alloc((size_t)NCLS * 4);
  float* up_ws = (float*)alloc((size_t)64 * D2 * 4);
  float* vp_ws = (float*)alloc((size_t)64 * D2 * 4);

  size_t fixed = (size_t)(p - (char*)d_ws);
  const size_t per_row = (size_t)D1 * 2 + (size_t)D2 * 2
                       + 2ULL * 64 * 4 + 2ULL * 32 * 4 + 2ULL * 16 * 4;
  int R = B_TOT;
  while (R > 1024 && fixed + (size_t)R * per_row + 4096 > ws_size) R >>= 1;

  f16* G1h = (f16*)alloc((size_t)R * D1 * 2);
  f16* G2h = (f16*)alloc((size_t)R * D2 * 2);
  float* ps1 = (float*)alloc((size_t)R * 64 * 4);
  float* pq1 = (float*)alloc((size_t)R * 64 * 4);
  float* ps2 = (float*)alloc((size_t)R * 32 * 4);
  float* pq2 = (float*)alloc((size_t)R * 32 * 4);
  float* ps3 = (float*)alloc((size_t)R * 16 * 4);
  float* pq3 = (float*)alloc((size_t)R * 16 * 4);
  float* praw = (float*)G1h;  // L3 writes praw after G1 is dead (in-order stream)

  float* out_ml = (float*)d_out;
  float* out_p  = out_ml + (size_t)B_TOT * NCLS;
  float* out_pr = out_p + (size_t)B_TOT * NCLS;

  // ---- prep (once per launch) ----
  hipLaunchKernelGGL(transpose_pair_kernel, dim3(D1 / 64, 1), dim3(256), 0, stream,
                     W1, (const float*)nullptr, (const float*)nullptr,
                     W1t_h, (f16*)nullptr, (float*)nullptr, (float*)nullptr, 32, D1);
  hipLaunchKernelGGL(transpose_pair_kernel, dim3(D2 / 64, D1 / 64), dim3(256), 0, stream,
                     W2, g1v, be1, W2t_h, (f16*)nullptr, up_ws, vp_ws, D1, D2);
  hipLaunchKernelGGL(uv_reduce_kernel, dim3(D2 / 256), dim3(256), 0, stream,
                     up_ws, vp_ws, u2, v2, D2, D1 / 64);
  hipLaunchKernelGGL(transpose_pair_kernel, dim3(D3 / 64, D2 / 64), dim3(256), 0, stream,
                     W3, g2v, be2, W3t_h, (f16*)nullptr, up_ws, vp_ws, D2, D3);
  hipLaunchKernelGGL(uv_reduce_kernel, dim3(D3 / 256), dim3(256), 0, stream,
                     up_ws, vp_ws, u3, v3, D3, D2 / 64);
  hipLaunchKernelGGL(w4g_kernel, dim3((D3 * NCLS + 255) / 256), dim3(256), 0, stream,
                     W4, g3v, w4g);
  hipLaunchKernelGGL(uv4_kernel, dim3(1), dim3(32), 0, stream, W4, g3v, be3, u4, v4);
  hipLaunchKernelGGL(pair_kernel, dim3((B_TOT * 32) / 256), dim3(256), 0, stream,
                     numeric, An_h, B_TOT * 32);

  for (int r0 = 0; r0 < B_TOT; r0 += R) {
    // layer 1: K=32 single-tile f16 GEMM + one-hot gathers
    hipLaunchKernelGGL(gemm1, dim3(D1 / 128, R / 128), dim3(256), 0, stream,
                       An_h + (size_t)r0 * 32, W1t_h, b1,
                       cat0 + r0, cat1 + r0, cat2 + r0, W1,
                       ps1, pq1, 64, G1h);
    // layer 2: plain f16 x f16, WM=2 (BM=128) -> 3 blocks/CU
    hipLaunchKernelGGL((gemm_ln<2, false, false, false>), dim3(D2 / 128, R / 128), dim3(512), 0, stream,
                       G1h, (const f16*)nullptr, W2t_h, (const f16*)nullptr,
                       D1, D2, b2, u2, v2,
                       ps1, pq1, 64, 1.0f / D1,
                       ps2, pq2, 32, G2h, (f16*)nullptr,
                       (const float*)nullptr, (float*)nullptr);
    // layer 3: plain f16 x f16, WM=2, fused head partials -> praw
    hipLaunchKernelGGL((gemm_ln<2, true, false, false>), dim3(D3 / 128, R / 128), dim3(512), 0, stream,
                       G2h, (const f16*)nullptr, W3t_h, (const f16*)nullptr,
                       D2, D3, b3, u3, v3,
                       ps2, pq2, 32, 1.0f / D2,
                       ps3, pq3, 16,
                       (f16*)nullptr, (f16*)nullptr, w4g, praw);
    // head
    hipLaunchKernelGGL(head_kernel, dim3(R / 4), dim3(256), 0, stream,
                       ps3, pq3, praw, u4, v4, b4, pid + r0, amask,
                       out_ml + (size_t)r0 * NCLS, out_p + (size_t)r0 * NCLS,
                       out_pr + r0, R);
  }
}

// Round 19
// 1554.456 us; speedup vs baseline: 1.7209x; 1.7209x over previous
//
#include <hip/hip_runtime.h>
#include <hip/hip_fp16.h>

#define B_TOT 32768
#define D1 4096
#define D2 2048
#define D3 1024
#define NCLS 19

typedef _Float16 f16;
typedef __attribute__((ext_vector_type(8))) _Float16 f16x8;
typedef __attribute__((ext_vector_type(4))) float f32x4;

// ---------------- helpers ----------------

__device__ __forceinline__ void gl_lds16(void* ldsDst, const void* gSrc) {
  __builtin_amdgcn_global_load_lds(
      (__attribute__((address_space(1))) void*)(void*)(gSrc),
      (__attribute__((address_space(3))) void*)(ldsDst),
      16, 0, 0);
}

__device__ __forceinline__ float gelu_f(float x) {
  return 0.5f * x * (1.0f + erff(x * 0.70710678118654752f));
}

// v ~= (float)h + (float)l * (1/4096)
__device__ __forceinline__ void mk_pair(float v, f16& h, f16& l) {
  f16 hh = (f16)v;
  h = hh;
  l = (f16)((v - (float)hh) * 4096.0f);
}

#define FENCE asm volatile("" ::: "memory")
#define BARRIER { FENCE; __builtin_amdgcn_s_barrier(); FENCE; }
#define WAITV6 asm volatile("s_waitcnt vmcnt(6)" ::: "memory")
#define WAITV5 asm volatile("s_waitcnt vmcnt(5)" ::: "memory")
#define WAITV4 asm volatile("s_waitcnt vmcnt(4)" ::: "memory")
#define WAITV3 asm volatile("s_waitcnt vmcnt(3)" ::: "memory")
#define WAITV2 asm volatile("s_waitcnt vmcnt(2)" ::: "memory")
#define WAITV0 asm volatile("s_waitcnt vmcnt(0)" ::: "memory")

// ---------------- prep kernels ----------------

// Transpose W -> Th [N][K] = gam[k]*W[k][n] (gam==nullptr -> 1), f16.
// If up != nullptr, ALSO emits per-k-block u/v partials (merged uv_part).
__global__ void transpose_pair_kernel(const float* __restrict__ W,
                                      const float* __restrict__ gam,
                                      const float* __restrict__ bet,
                                      f16* __restrict__ Th, f16* __restrict__ Tl,
                                      float* __restrict__ up, float* __restrict__ vp,
                                      int K, int N) {
  __shared__ float t[64][65];
  __shared__ float su4[4][64], sv4[4][64];
  int k0 = blockIdx.y * 64, n0 = blockIdx.x * 64;
  int tx = threadIdx.x & 63, ty = threadIdx.x >> 6;
#pragma unroll
  for (int i = 0; i < 16; ++i) {
    int kl = ty + i * 4;
    int kk = k0 + kl;
    if (kk < K) t[kl][tx] = W[(size_t)kk * N + n0 + tx];   // raw W
  }
  __syncthreads();
  if (up) {
    float su = 0.f, sv = 0.f;
#pragma unroll
    for (int i = 0; i < 16; ++i) {
      int kl = ty + i * 4;
      int kk = k0 + kl;
      if (kk < K) {
        float w = t[kl][tx];
        su += gam[kk] * w;
        sv += bet[kk] * w;
      }
    }
    su4[ty][tx] = su; sv4[ty][tx] = sv;
  }
  __syncthreads();
#pragma unroll
  for (int i = 0; i < 16; ++i) {
    int nl = ty + i * 4;
    int kk = k0 + tx;
    if (kk < K) {
      float s = gam ? gam[kk] : 1.0f;
      float v = s * t[tx][nl];
      f16 h, l; mk_pair(v, h, l);
      size_t o = (size_t)(n0 + nl) * K + kk;
      Th[o] = h;
      if (Tl) Tl[o] = l;
    }
  }
  if (up && ty == 0) {
    float su = su4[0][tx] + su4[1][tx] + su4[2][tx] + su4[3][tx];
    float sv = sv4[0][tx] + sv4[1][tx] + sv4[2][tx] + sv4[3][tx];
    up[(size_t)blockIdx.y * N + n0 + tx] = su;
    vp[(size_t)blockIdx.y * N + n0 + tx] = sv;
  }
}

// w4g[k][c] = gam3[k] * W4[k][c]
__global__ void w4g_kernel(const float* __restrict__ W4, const float* __restrict__ gam,
                           float* __restrict__ w4g) {
  int i = blockIdx.x * 256 + threadIdx.x;
  if (i < D3 * NCLS) w4g[i] = gam[i / NCLS] * W4[i];
}

// u4[c] = sum_k gam3[k]*W4[k][c]; v4[c] = sum_k bet3[k]*W4[k][c]
__global__ void uv4_kernel(const float* __restrict__ W4, const float* __restrict__ gam,
                           const float* __restrict__ bet,
                           float* __restrict__ u4, float* __restrict__ v4) {
  int c = threadIdx.x;
  if (c >= NCLS) return;
  float su = 0.f, sv = 0.f;
  for (int k = 0; k < D3; ++k) {
    float w = W4[(size_t)k * NCLS + c];
    su += gam[k] * w;
    sv += bet[k] * w;
  }
  u4[c] = su; v4[c] = sv;
}

__global__ void uv_reduce_kernel(const float* __restrict__ up, const float* __restrict__ vp,
                                 float* __restrict__ u, float* __restrict__ v,
                                 int N, int nc) {
  int n = blockIdx.x * 256 + threadIdx.x;
  if (n >= N) return;
  float su = 0.f, sv = 0.f;
  for (int c = 0; c < nc; ++c) {
    su += up[(size_t)c * N + n];
    sv += vp[(size_t)c * N + n];
  }
  u[n] = su; v[n] = sv;
}

__global__ void pair_kernel(const float* __restrict__ x, f16* __restrict__ h, int n) {
  int i = blockIdx.x * 256 + threadIdx.x;
  if (i < n) h[i] = (f16)x[i];
}

// ---------------- layer-1 GEMM (K=32 single tile + one-hot gathers), f16 x f16 ----------------

__global__ __launch_bounds__(256, 4)
void gemm1(const f16* __restrict__ Ah, const f16* __restrict__ Bh,
           const float* __restrict__ bias,
           const int* __restrict__ c0, const int* __restrict__ c1,
           const int* __restrict__ c2, const float* __restrict__ W1raw,
           float* __restrict__ part_s, float* __restrict__ part_q, int nparts,
           f16* __restrict__ Gh) {
  constexpr int K = 32, N = D1;
  __shared__ __align__(16) f16 AhS[128 * 32];
  __shared__ __align__(16) f16 BhS[128 * 32];

  const int tid = threadIdx.x;
  const int wave = tid >> 6, lane = tid & 63;
  const int wr = wave >> 1, wc = wave & 1;
  const int lq = lane >> 4, lr = lane & 15;

  const int gx = gridDim.x;
  const int nwg = gx * gridDim.y;
  const int flat = blockIdx.y * gx + blockIdx.x;
  const int cpx = nwg >> 3;
  const int swz = (flat & 7) * cpx + (flat >> 3);
  const int bx = swz % gx, by = swz / gx;
  const int m0 = by * 128, n0 = bx * 128;

#pragma unroll
  for (int i = 0; i < 2; ++i) {
    int idx = i * 256 + tid;
    int rr = idx >> 2, kq = idx & 3;
    int kqg = kq ^ ((rr >> 1) & 3);
    gl_lds16(&AhS[idx * 8], Ah + (size_t)(m0 + rr) * K + kqg * 8);
    gl_lds16(&BhS[idx * 8], Bh + (size_t)(n0 + rr) * K + kqg * 8);
  }
  WAITV0;
  BARRIER;

  f32x4 acc0[4][4];
  const f32x4 vz = {0.f, 0.f, 0.f, 0.f};
#pragma unroll
  for (int a = 0; a < 4; ++a)
#pragma unroll
    for (int b = 0; b < 4; ++b) acc0[a][b] = vz;

  f16x8 af[4], bf[4];
#pragma unroll
  for (int mf = 0; mf < 4; ++mf) {
    int row = wr * 64 + mf * 16 + lr;
    int ca = lq ^ ((row >> 1) & 3);
    af[mf] = *(const f16x8*)(&AhS[row * 32 + ca * 8]);
  }
#pragma unroll
  for (int nf = 0; nf < 4; ++nf) {
    int col = wc * 64 + nf * 16 + lr;
    int cb = lq ^ ((col >> 1) & 3);
    bf[nf] = *(const f16x8*)(&BhS[col * 32 + cb * 8]);
  }
#pragma unroll
  for (int mf = 0; mf < 4; ++mf)
#pragma unroll
    for (int nf = 0; nf < 4; ++nf)
      acc0[mf][nf] = __builtin_amdgcn_mfma_f32_16x16x32_f16(af[mf], bf[nf], acc0[mf][nf], 0, 0, 0);

  const int pidx = bx * 2 + wc;
#pragma unroll
  for (int mf = 0; mf < 4; ++mf) {
#pragma unroll
    for (int j = 0; j < 4; ++j) {
      const int row = m0 + wr * 64 + mf * 16 + lq * 4 + j;
      const int g0 = 32 + c0[row], g1i = 96 + c1[row], g2i = 224 + c2[row];
      float rowsum = 0.f, rowsq = 0.f;
#pragma unroll
      for (int nf = 0; nf < 4; ++nf) {
        const int col = n0 + wc * 64 + nf * 16 + lr;
        float pre = acc0[mf][nf][j] + bias[col]
                  + W1raw[(size_t)g0 * D1 + col]
                  + W1raw[(size_t)g1i * D1 + col]
                  + W1raw[(size_t)g2i * D1 + col];
        float g = gelu_f(pre);
        Gh[(size_t)row * N + col] = (f16)g;
        rowsum += g; rowsq += g * g;
      }
#pragma unroll
      for (int off = 1; off < 16; off <<= 1) {
        rowsum += __shfl_xor(rowsum, off);
        rowsq  += __shfl_xor(rowsq, off);
      }
      if (lr == 0) {
        part_s[(size_t)row * nparts + pidx] = rowsum;
        part_q[(size_t)row * nparts + pidx] = rowsq;
      }
    }
  }
}

// ---------------- pipelined f16 GEMM (layers 2/3) — round-7 proven schedule ----------------
// r19: WM=2 both layers, DEFAULT __launch_bounds__(512, 2) — NO register cap.
// r18 post-mortem: (512,6) forced VGPR=40 -> massive scratch spills (1.8 GB
// writes/dispatch, MfmaUtil 3.5%). WM=2 at natural ~60 VGPR fits 6 waves/EU
// anyway (<= 84), and 49 KB LDS permits 3 blocks/CU by LDS — occupancy
// without the cap footgun.
// Loads/tile LD = (WM/2)*(1+ALO) + 1 + BLO; entry wait vmcnt(LD).
// FUSE=true (L3): epilogue emits per-(row, col-block) 19-wide partial logit
// dots (LN3 affine fold) and skips the G3 store entirely.

template <int WM, bool FUSE, bool BLO, bool ALO>
__global__ __launch_bounds__(512, 2)
void gemm_ln(const f16* __restrict__ Ah, const f16* __restrict__ Al,
             const f16* __restrict__ Bh, const f16* __restrict__ Bl,
             int K, int N,
             const float* __restrict__ bias,
             const float* __restrict__ uvec, const float* __restrict__ vvec,
             const float* __restrict__ ps_in, const float* __restrict__ pq_in,
             int np_, float invN,
             float* __restrict__ part_s, float* __restrict__ part_q, int nparts,
             f16* __restrict__ Gh, f16* __restrict__ Gl,
             const float* __restrict__ w4g, float* __restrict__ praw) {
  constexpr int BM = WM * 64;
  constexpr bool USE1 = ALO || BLO;
  __shared__ __align__(16) f16 AhS[3 * BM * 32];
  __shared__ __align__(16) f16 AlS[ALO ? 3 * BM * 32 : 16];
  __shared__ __align__(16) f16 BhS[3 * 128 * 32];
  __shared__ __align__(16) f16 BlS[BLO ? 3 * 128 * 32 : 16];
  __shared__ float mS[BM], rsS[BM];

  const int tid = threadIdx.x;
  const int wave = tid >> 6, lane = tid & 63;
  const int wr = wave >> 1, wc = wave & 1;
  const int lq = lane >> 4, lr = lane & 15;

  const int gx = gridDim.x;
  const int nwg = gx * gridDim.y;
  const int flat = blockIdx.y * gx + blockIdx.x;
  const int cpx = nwg >> 3;
  const int swz = (flat & 7) * cpx + (flat >> 3);
  const int bx = swz % gx, by = swz / gx;
  const int m0 = by * BM, n0 = bx * 128;

  // ---- in-kernel LN stats for this block's rows ----
  for (int r = tid; r < BM; r += 512) {
    const float* pr = ps_in + (size_t)(m0 + r) * np_;
    const float* qr = pq_in + (size_t)(m0 + r) * np_;
    float s = 0.f, q = 0.f;
    for (int pp = 0; pp < np_; pp += 4) {
      float4 a = *(const float4*)(pr + pp);
      float4 b = *(const float4*)(qr + pp);
      s += a.x + a.y + a.z + a.w;
      q += b.x + b.y + b.z + b.w;
    }
    float mean = s * invN;
    mS[r] = mean;
    rsS[r] = 1.0f / sqrtf(q * invN - mean * mean + 1e-5f);
  }

  f32x4 acc0[WM][4], acc1[USE1 ? WM : 1][4];
  const f32x4 vz = {0.f, 0.f, 0.f, 0.f};
#pragma unroll
  for (int a = 0; a < WM; ++a)
#pragma unroll
    for (int b = 0; b < 4; ++b) {
      acc0[a][b] = vz;
      if constexpr (USE1) acc1[a][b] = vz;
    }

  const int nkt = K >> 5;

  auto stage0 = [&](int b, int kt_) {
    const int k0_ = kt_ << 5;
#pragma unroll
    for (int r = 0; r < WM / 2; ++r) {
      int idx = r * 512 + tid, rr = idx >> 2, kq = idx & 3;
      int kqg = kq ^ ((rr >> 1) & 3);
      gl_lds16(&AhS[b * (BM * 32) + idx * 8], Ah + (size_t)(m0 + rr) * K + k0_ + kqg * 8);
    }
    { int rr = tid >> 2, kq = tid & 3, kqg = kq ^ ((rr >> 1) & 3);
      gl_lds16(&BhS[b * (128 * 32) + tid * 8], Bh + (size_t)(n0 + rr) * K + k0_ + kqg * 8); }
  };
  auto stage1 = [&](int b, int kt_) {
    const int k0_ = kt_ << 5;
    if constexpr (ALO) {
#pragma unroll
      for (int r = 0; r < WM / 2; ++r) {
        int idx = r * 512 + tid, rr = idx >> 2, kq = idx & 3;
        int kqg = kq ^ ((rr >> 1) & 3);
        gl_lds16(&AlS[b * (BM * 32) + idx * 8], Al + (size_t)(m0 + rr) * K + k0_ + kqg * 8);
      }
    }
    if constexpr (BLO) {
      int rr = tid >> 2, kq = tid & 3, kqg = kq ^ ((rr >> 1) & 3);
      gl_lds16(&BlS[b * (128 * 32) + tid * 8], Bl + (size_t)(n0 + rr) * K + k0_ + kqg * 8);
    }
  };

  // prologue: tiles 0 and 1 in flight
  stage0(0, 0);
  if constexpr (USE1) stage1(0, 0);
  if (nkt > 1) { stage0(1, 1); if constexpr (USE1) stage1(1, 1); }

  for (int t = 0; t < nkt; ++t) {
    const int cb = t % 3;              // compute buffer
    const int sb = (t + 2) % 3;        // stage target (== buffer of t-1)
    if (t + 1 < nkt) {
      constexpr int LD = (WM / 2) * (1 + (ALO ? 1 : 0)) + 1 + (BLO ? 1 : 0);
      if constexpr (LD >= 6) { WAITV6; }
      else if constexpr (LD == 5) { WAITV5; }
      else if constexpr (LD == 4) { WAITV4; }
      else if constexpr (LD == 3) { WAITV3; }
      else { WAITV2; }
    } else {
      WAITV0;
    }
    BARRIER;

    const bool pf = (t + 2 < nkt);

    f16x8 bf[4], blf[4];
#pragma unroll
    for (int ph = 0; ph < WM / 2; ++ph) {
      const int mfA = ph * 2, mfB = ph * 2 + 1;
      f16x8 aA, aAl, aB, aBl;
      {
        int rowA = wr * (WM * 16) + mfA * 16 + lr;
        int caA = lq ^ ((rowA >> 1) & 3);
        aA = *(const f16x8*)(&AhS[cb * (BM * 32) + rowA * 32 + caA * 8]);
        if constexpr (ALO) aAl = *(const f16x8*)(&AlS[cb * (BM * 32) + rowA * 32 + caA * 8]);
        int rowB = wr * (WM * 16) + mfB * 16 + lr;
        int caB = lq ^ ((rowB >> 1) & 3);
        aB = *(const f16x8*)(&AhS[cb * (BM * 32) + rowB * 32 + caB * 8]);
        if constexpr (ALO) aBl = *(const f16x8*)(&AlS[cb * (BM * 32) + rowB * 32 + caB * 8]);
      }
      if (ph == 0) {
#pragma unroll
        for (int nf = 0; nf < 4; ++nf) {
          int col = wc * 64 + nf * 16 + lr;
          int cc = lq ^ ((col >> 1) & 3);
          bf[nf] = *(const f16x8*)(&BhS[cb * (128 * 32) + col * 32 + cc * 8]);
          if constexpr (BLO)
            blf[nf] = *(const f16x8*)(&BlS[cb * (128 * 32) + col * 32 + cc * 8]);
        }
      }
      if (pf) {
        if (ph == 0) { stage0(sb, t + 2); if (WM == 2) { if constexpr (USE1) stage1(sb, t + 2); } }
        if (ph == 1) { if constexpr (USE1) stage1(sb, t + 2); }
      }
      BARRIER;
      __builtin_amdgcn_s_setprio(1);
#pragma unroll
      for (int nf = 0; nf < 4; ++nf) {
        acc0[mfA][nf] = __builtin_amdgcn_mfma_f32_16x16x32_f16(aA, bf[nf], acc0[mfA][nf], 0, 0, 0);
        if constexpr (BLO)
          acc1[mfA][nf] = __builtin_amdgcn_mfma_f32_16x16x32_f16(aA, blf[nf], acc1[mfA][nf], 0, 0, 0);
        if constexpr (ALO)
          acc1[mfA][nf] = __builtin_amdgcn_mfma_f32_16x16x32_f16(aAl, bf[nf], acc1[mfA][nf], 0, 0, 0);
      }
#pragma unroll
      for (int nf = 0; nf < 4; ++nf) {
        acc0[mfB][nf] = __builtin_amdgcn_mfma_f32_16x16x32_f16(aB, bf[nf], acc0[mfB][nf], 0, 0, 0);
        if constexpr (BLO)
          acc1[mfB][nf] = __builtin_amdgcn_mfma_f32_16x16x32_f16(aB, blf[nf], acc1[mfB][nf], 0, 0, 0);
        if constexpr (ALO)
          acc1[mfB][nf] = __builtin_amdgcn_mfma_f32_16x16x32_f16(aBl, bf[nf], acc1[mfB][nf], 0, 0, 0);
      }
      __builtin_amdgcn_s_setprio(0);
    }
  }

  // ---- epilogue: LN fold + gelu + (store | fused logit partials) ----
  const int pidx = bx * 2 + wc;
#pragma unroll
  for (int mf = 0; mf < WM; ++mf) {
#pragma unroll
    for (int j = 0; j < 4; ++j) {
      const int rl = wr * (WM * 16) + mf * 16 + lq * 4 + j;
      const int row = m0 + rl;
      const float mA = mS[rl], rsA = rsS[rl];
      float gval[4];
      float rowsum = 0.f, rowsq = 0.f;
#pragma unroll
      for (int nf = 0; nf < 4; ++nf) {
        const int col = n0 + wc * 64 + nf * 16 + lr;
        float val = acc0[mf][nf][j];
        if constexpr (USE1) val += acc1[mf][nf][j] * (1.0f / 4096.0f);
        float pre = rsA * val - rsA * mA * uvec[col] + vvec[col] + bias[col];
        float g = gelu_f(pre);
        gval[nf] = g;
        if constexpr (!FUSE) {
          f16 h, l; mk_pair(g, h, l);
          size_t o = (size_t)row * N + col;
          Gh[o] = h;
          if (Gl) Gl[o] = l;
        }
        rowsum += g; rowsq += g * g;
      }
      float lacc[NCLS];
      if constexpr (FUSE) {
#pragma unroll
        for (int c = 0; c < NCLS; ++c) lacc[c] = 0.f;
#pragma unroll
        for (int nf = 0; nf < 4; ++nf) {
          const int col = n0 + wc * 64 + nf * 16 + lr;
          const float* wrow = w4g + (size_t)col * NCLS;
          const float gv = gval[nf];
#pragma unroll
          for (int c = 0; c < NCLS; ++c) lacc[c] += gv * wrow[c];
        }
#pragma unroll
        for (int off = 1; off < 16; off <<= 1) {
#pragma unroll
          for (int c = 0; c < NCLS; ++c) lacc[c] += __shfl_xor(lacc[c], off);
        }
      }
#pragma unroll
      for (int off = 1; off < 16; off <<= 1) {
        rowsum += __shfl_xor(rowsum, off);
        rowsq  += __shfl_xor(rowsq, off);
      }
      if (lr == 0) {
        part_s[(size_t)row * nparts + pidx] = rowsum;
        part_q[(size_t)row * nparts + pidx] = rowsq;
        if constexpr (FUSE) {
          float* pw = praw + ((size_t)row * 16 + pidx) * NCLS;
#pragma unroll
          for (int c = 0; c < NCLS; ++c) pw[c] = lacc[c];
        }
      }
    }
  }
}

// ---------------- head: combine partial dots + LN3 affine + mask + softmax + argmax ----

__global__ __launch_bounds__(256)
void head_kernel(const float* __restrict__ ps3, const float* __restrict__ pq3,
                 const float* __restrict__ praw,
                 const float* __restrict__ u4, const float* __restrict__ v4,
                 const float* __restrict__ b4,
                 const int* __restrict__ pid, const float* __restrict__ amask,
                 float* __restrict__ out_ml, float* __restrict__ out_p,
                 float* __restrict__ out_pred, int rows) {
  const int wave = threadIdx.x >> 6, lane = threadIdx.x & 63;
  const int r = blockIdx.x * 4 + wave;
  if (r >= rows) return;
  const int lp = lane & 15;
  float s = ps3[(size_t)r * 16 + lp];
  float q = pq3[(size_t)r * 16 + lp];
  float acc[NCLS];
  {
    const float* pr = praw + ((size_t)r * 16 + lp) * NCLS;
#pragma unroll
    for (int c = 0; c < NCLS; ++c) acc[c] = pr[c];
  }
#pragma unroll
  for (int off = 1; off < 16; off <<= 1) {
    s += __shfl_xor(s, off);
    q += __shfl_xor(q, off);
#pragma unroll
    for (int c = 0; c < NCLS; ++c) acc[c] += __shfl_xor(acc[c], off);
  }
  const float invN3 = 1.0f / (float)D3;
  const float m = s * invN3;
  const float rs = 1.0f / sqrtf(q * invN3 - m * m + 1e-5f);

  const int p = pid[r];
  float ml[NCLS], mx = -3.4e38f;
#pragma unroll
  for (int c = 0; c < NCLS; ++c) {
    ml[c] = rs * acc[c] - rs * m * u4[c] + v4[c] + b4[c] + amask[(size_t)p * NCLS + c];
    mx = fmaxf(mx, ml[c]);
  }
  float ex[NCLS], ssum = 0.f;
#pragma unroll
  for (int c = 0; c < NCLS; ++c) { ex[c] = expf(ml[c] - mx); ssum += ex[c]; }
  const float inv = 1.0f / ssum;
  float pr2[NCLS];
#pragma unroll
  for (int c = 0; c < NCLS; ++c) pr2[c] = ex[c] * inv;
  int best = 0; float bp = pr2[0];
#pragma unroll
  for (int c = 1; c < NCLS; ++c) { if (pr2[c] > bp) { bp = pr2[c]; best = c; } }
  if (lane < NCLS) {
    out_ml[(size_t)r * NCLS + lane] = ml[lane];
    out_p [(size_t)r * NCLS + lane] = pr2[lane];
  }
  if (lane == 0) out_pred[r] = (float)best;
}

// ---------------- host ----------------

extern "C" void kernel_launch(void* const* d_in, const int* in_sizes, int n_in,
                              void* d_out, int out_size, void* d_ws, size_t ws_size,
                              hipStream_t stream) {
  const float* numeric = (const float*)d_in[0];
  const int*   cat0 = (const int*)d_in[1];
  const int*   cat1 = (const int*)d_in[2];
  const int*   cat2 = (const int*)d_in[3];
  const int*   pid  = (const int*)d_in[4];
  const float* amask= (const float*)d_in[5];
  const float* W1 = (const float*)d_in[6];
  const float* b1 = (const float*)d_in[7];
  const float* g1v= (const float*)d_in[8];
  const float* be1= (const float*)d_in[9];
  const float* W2 = (const float*)d_in[10];
  const float* b2 = (const float*)d_in[11];
  const float* g2v= (const float*)d_in[12];
  const float* be2= (const float*)d_in[13];
  const float* W3 = (const float*)d_in[14];
  const float* b3 = (const float*)d_in[15];
  const float* g3v= (const float*)d_in[16];
  const float* be3= (const float*)d_in[17];
  const float* W4 = (const float*)d_in[18];
  const float* b4 = (const float*)d_in[19];
  (void)in_sizes; (void)n_in; (void)out_size;

  char* p = (char*)d_ws;
  auto alloc = [&](size_t bytes) -> char* {
    char* r = p;
    p += (bytes + 255) & ~(size_t)255;
    return r;
  };

  // fixed workspace
  f16* W1t_h = (f16*)alloc((size_t)D1 * 32 * 2);
  f16* W2t_h = (f16*)alloc((size_t)D2 * D1 * 2);
  f16* W3t_h = (f16*)alloc((size_t)D3 * D2 * 2);
  f16* An_h  = (f16*)alloc((size_t)B_TOT * 32 * 2);
  float* u2  = (float*)alloc((size_t)D2 * 4);
  float* v2  = (float*)alloc((size_t)D2 * 4);
  float* u3  = (float*)alloc((size_t)D3 * 4);
  float* v3  = (float*)alloc((size_t)D3 * 4);
  float* w4g = (float*)alloc((size_t)D3 * NCLS * 4);
  float* u4  = (float*)alloc((size_t)NCLS * 4);
  float* v4  = (float*)alloc((size_t)NCLS * 4);
  float* up_ws = (float*)alloc((size_t)64 * D2 * 4);
  float* vp_ws = (float*)alloc((size_t)64 * D2 * 4);

  size_t fixed = (size_t)(p - (char*)d_ws);
  const size_t per_row = (size_t)D1 * 2 + (size_t)D2 * 2
                       + 2ULL * 64 * 4 + 2ULL * 32 * 4 + 2ULL * 16 * 4;
  int R = B_TOT;
  while (R > 1024 && fixed + (size_t)R * per_row + 4096 > ws_size) R >>= 1;

  f16* G1h = (f16*)alloc((size_t)R * D1 * 2);
  f16* G2h = (f16*)alloc((size_t)R * D2 * 2);
  float* ps1 = (float*)alloc((size_t)R * 64 * 4);
  float* pq1 = (float*)alloc((size_t)R * 64 * 4);
  float* ps2 = (float*)alloc((size_t)R * 32 * 4);
  float* pq2 = (float*)alloc((size_t)R * 32 * 4);
  float* ps3 = (float*)alloc((size_t)R * 16 * 4);
  float* pq3 = (float*)alloc((size_t)R * 16 * 4);
  float* praw = (float*)G1h;  // L3 writes praw after G1 is dead (in-order stream)

  float* out_ml = (float*)d_out;
  float* out_p  = out_ml + (size_t)B_TOT * NCLS;
  float* out_pr = out_p + (size_t)B_TOT * NCLS;

  // ---- prep (once per launch) ----
  hipLaunchKernelGGL(transpose_pair_kernel, dim3(D1 / 64, 1), dim3(256), 0, stream,
                     W1, (const float*)nullptr, (const float*)nullptr,
                     W1t_h, (f16*)nullptr, (float*)nullptr, (float*)nullptr, 32, D1);
  hipLaunchKernelGGL(transpose_pair_kernel, dim3(D2 / 64, D1 / 64), dim3(256), 0, stream,
                     W2, g1v, be1, W2t_h, (f16*)nullptr, up_ws, vp_ws, D1, D2);
  hipLaunchKernelGGL(uv_reduce_kernel, dim3(D2 / 256), dim3(256), 0, stream,
                     up_ws, vp_ws, u2, v2, D2, D1 / 64);
  hipLaunchKernelGGL(transpose_pair_kernel, dim3(D3 / 64, D2 / 64), dim3(256), 0, stream,
                     W3, g2v, be2, W3t_h, (f16*)nullptr, up_ws, vp_ws, D2, D3);
  hipLaunchKernelGGL(uv_reduce_kernel, dim3(D3 / 256), dim3(256), 0, stream,
                     up_ws, vp_ws, u3, v3, D3, D2 / 64);
  hipLaunchKernelGGL(w4g_kernel, dim3((D3 * NCLS + 255) / 256), dim3(256), 0, stream,
                     W4, g3v, w4g);
  hipLaunchKernelGGL(uv4_kernel, dim3(1), dim3(32), 0, stream, W4, g3v, be3, u4, v4);
  hipLaunchKernelGGL(pair_kernel, dim3((B_TOT * 32) / 256), dim3(256), 0, stream,
                     numeric, An_h, B_TOT * 32);

  for (int r0 = 0; r0 < B_TOT; r0 += R) {
    // layer 1: K=32 single-tile f16 GEMM + one-hot gathers
    hipLaunchKernelGGL(gemm1, dim3(D1 / 128, R / 128), dim3(256), 0, stream,
                       An_h + (size_t)r0 * 32, W1t_h, b1,
                       cat0 + r0, cat1 + r0, cat2 + r0, W1,
                       ps1, pq1, 64, G1h);
    // layer 2: plain f16 x f16, WM=2 (49 KB LDS; no register cap)
    hipLaunchKernelGGL((gemm_ln<2, false, false, false>), dim3(D2 / 128, R / 128), dim3(512), 0, stream,
                       G1h, (const f16*)nullptr, W2t_h, (const f16*)nullptr,
                       D1, D2, b2, u2, v2,
                       ps1, pq1, 64, 1.0f / D1,
                       ps2, pq2, 32, G2h, (f16*)nullptr,
                       (const float*)nullptr, (float*)nullptr);
    // layer 3: plain f16 x f16, WM=2, fused head partials -> praw
    hipLaunchKernelGGL((gemm_ln<2, true, false, false>), dim3(D3 / 128, R / 128), dim3(512), 0, stream,
                       G2h, (const f16*)nullptr, W3t_h, (const f16*)nullptr,
                       D2, D3, b3, u3, v3,
                       ps2, pq2, 32, 1.0f / D2,
                       ps3, pq3, 16,
                       (f16*)nullptr, (f16*)nullptr, w4g, praw);
    // head
    hipLaunchKernelGGL(head_kernel, dim3(R / 4), dim3(256), 0, stream,
                       ps3, pq3, praw, u4, v4, b4, pid + r0, amask,
                       out_ml + (size_t)r0 * NCLS, out_p + (size_t)r0 * NCLS,
                       out_pr + r0, R);
  }
}

// Round 20
// 1479.005 us; speedup vs baseline: 1.8086x; 1.0510x over previous
//
#include <hip/hip_runtime.h>
#include <hip/hip_fp16.h>

#define B_TOT 32768
#define D1 4096
#define D2 2048
#define D3 1024
#define NCLS 19

typedef _Float16 f16;
typedef __attribute__((ext_vector_type(8))) _Float16 f16x8;
typedef __attribute__((ext_vector_type(4))) float f32x4;

// ---------------- helpers ----------------

__device__ __forceinline__ void gl_lds16(void* ldsDst, const void* gSrc) {
  __builtin_amdgcn_global_load_lds(
      (__attribute__((address_space(1))) void*)(void*)(gSrc),
      (__attribute__((address_space(3))) void*)(ldsDst),
      16, 0, 0);
}

__device__ __forceinline__ float gelu_f(float x) {
  return 0.5f * x * (1.0f + erff(x * 0.70710678118654752f));
}

// v ~= (float)h + (float)l * (1/4096)
__device__ __forceinline__ void mk_pair(float v, f16& h, f16& l) {
  f16 hh = (f16)v;
  h = hh;
  l = (f16)((v - (float)hh) * 4096.0f);
}

#define FENCE asm volatile("" ::: "memory")
#define BARRIER { FENCE; __builtin_amdgcn_s_barrier(); FENCE; }
#define WAITV6 asm volatile("s_waitcnt vmcnt(6)" ::: "memory")
#define WAITV5 asm volatile("s_waitcnt vmcnt(5)" ::: "memory")
#define WAITV4 asm volatile("s_waitcnt vmcnt(4)" ::: "memory")
#define WAITV3 asm volatile("s_waitcnt vmcnt(3)" ::: "memory")
#define WAITV2 asm volatile("s_waitcnt vmcnt(2)" ::: "memory")
#define WAITV0 asm volatile("s_waitcnt vmcnt(0)" ::: "memory")

// ---------------- prep kernels ----------------

// Transpose W -> Th [N][K] = gam[k]*W[k][n] (gam==nullptr -> 1), f16.
// If up != nullptr, ALSO emits per-k-block u/v partials (merged uv_part).
__global__ void transpose_pair_kernel(const float* __restrict__ W,
                                      const float* __restrict__ gam,
                                      const float* __restrict__ bet,
                                      f16* __restrict__ Th, f16* __restrict__ Tl,
                                      float* __restrict__ up, float* __restrict__ vp,
                                      int K, int N) {
  __shared__ float t[64][65];
  __shared__ float su4[4][64], sv4[4][64];
  int k0 = blockIdx.y * 64, n0 = blockIdx.x * 64;
  int tx = threadIdx.x & 63, ty = threadIdx.x >> 6;
#pragma unroll
  for (int i = 0; i < 16; ++i) {
    int kl = ty + i * 4;
    int kk = k0 + kl;
    if (kk < K) t[kl][tx] = W[(size_t)kk * N + n0 + tx];   // raw W
  }
  __syncthreads();
  if (up) {
    float su = 0.f, sv = 0.f;
#pragma unroll
    for (int i = 0; i < 16; ++i) {
      int kl = ty + i * 4;
      int kk = k0 + kl;
      if (kk < K) {
        float w = t[kl][tx];
        su += gam[kk] * w;
        sv += bet[kk] * w;
      }
    }
    su4[ty][tx] = su; sv4[ty][tx] = sv;
  }
  __syncthreads();
#pragma unroll
  for (int i = 0; i < 16; ++i) {
    int nl = ty + i * 4;
    int kk = k0 + tx;
    if (kk < K) {
      float s = gam ? gam[kk] : 1.0f;
      float v = s * t[tx][nl];
      f16 h, l; mk_pair(v, h, l);
      size_t o = (size_t)(n0 + nl) * K + kk;
      Th[o] = h;
      if (Tl) Tl[o] = l;
    }
  }
  if (up && ty == 0) {
    float su = su4[0][tx] + su4[1][tx] + su4[2][tx] + su4[3][tx];
    float sv = sv4[0][tx] + sv4[1][tx] + sv4[2][tx] + sv4[3][tx];
    up[(size_t)blockIdx.y * N + n0 + tx] = su;
    vp[(size_t)blockIdx.y * N + n0 + tx] = sv;
  }
}

// w4g[k][c] = gam3[k] * W4[k][c]
__global__ void w4g_kernel(const float* __restrict__ W4, const float* __restrict__ gam,
                           float* __restrict__ w4g) {
  int i = blockIdx.x * 256 + threadIdx.x;
  if (i < D3 * NCLS) w4g[i] = gam[i / NCLS] * W4[i];
}

// u4[c] = sum_k gam3[k]*W4[k][c]; v4[c] = sum_k bet3[k]*W4[k][c]
__global__ void uv4_kernel(const float* __restrict__ W4, const float* __restrict__ gam,
                           const float* __restrict__ bet,
                           float* __restrict__ u4, float* __restrict__ v4) {
  int c = threadIdx.x;
  if (c >= NCLS) return;
  float su = 0.f, sv = 0.f;
  for (int k = 0; k < D3; ++k) {
    float w = W4[(size_t)k * NCLS + c];
    su += gam[k] * w;
    sv += bet[k] * w;
  }
  u4[c] = su; v4[c] = sv;
}

__global__ void uv_reduce_kernel(const float* __restrict__ up, const float* __restrict__ vp,
                                 float* __restrict__ u, float* __restrict__ v,
                                 int N, int nc) {
  int n = blockIdx.x * 256 + threadIdx.x;
  if (n >= N) return;
  float su = 0.f, sv = 0.f;
  for (int c = 0; c < nc; ++c) {
    su += up[(size_t)c * N + n];
    sv += vp[(size_t)c * N + n];
  }
  u[n] = su; v[n] = sv;
}

__global__ void pair_kernel(const float* __restrict__ x, f16* __restrict__ h, int n) {
  int i = blockIdx.x * 256 + threadIdx.x;
  if (i < n) h[i] = (f16)x[i];
}

// ---------------- layer-1 GEMM (K=32 single tile + one-hot gathers), f16 x f16 ----------------

__global__ __launch_bounds__(256, 4)
void gemm1(const f16* __restrict__ Ah, const f16* __restrict__ Bh,
           const float* __restrict__ bias,
           const int* __restrict__ c0, const int* __restrict__ c1,
           const int* __restrict__ c2, const float* __restrict__ W1raw,
           float* __restrict__ part_s, float* __restrict__ part_q, int nparts,
           f16* __restrict__ Gh) {
  constexpr int K = 32, N = D1;
  __shared__ __align__(16) f16 AhS[128 * 32];
  __shared__ __align__(16) f16 BhS[128 * 32];

  const int tid = threadIdx.x;
  const int wave = tid >> 6, lane = tid & 63;
  const int wr = wave >> 1, wc = wave & 1;
  const int lq = lane >> 4, lr = lane & 15;

  const int gx = gridDim.x;
  const int nwg = gx * gridDim.y;
  const int flat = blockIdx.y * gx + blockIdx.x;
  const int cpx = nwg >> 3;
  const int swz = (flat & 7) * cpx + (flat >> 3);
  const int bx = swz % gx, by = swz / gx;
  const int m0 = by * 128, n0 = bx * 128;

#pragma unroll
  for (int i = 0; i < 2; ++i) {
    int idx = i * 256 + tid;
    int rr = idx >> 2, kq = idx & 3;
    int kqg = kq ^ ((rr >> 1) & 3);
    gl_lds16(&AhS[idx * 8], Ah + (size_t)(m0 + rr) * K + kqg * 8);
    gl_lds16(&BhS[idx * 8], Bh + (size_t)(n0 + rr) * K + kqg * 8);
  }
  WAITV0;
  BARRIER;

  f32x4 acc0[4][4];
  const f32x4 vz = {0.f, 0.f, 0.f, 0.f};
#pragma unroll
  for (int a = 0; a < 4; ++a)
#pragma unroll
    for (int b = 0; b < 4; ++b) acc0[a][b] = vz;

  f16x8 af[4], bf[4];
#pragma unroll
  for (int mf = 0; mf < 4; ++mf) {
    int row = wr * 64 + mf * 16 + lr;
    int ca = lq ^ ((row >> 1) & 3);
    af[mf] = *(const f16x8*)(&AhS[row * 32 + ca * 8]);
  }
#pragma unroll
  for (int nf = 0; nf < 4; ++nf) {
    int col = wc * 64 + nf * 16 + lr;
    int cb = lq ^ ((col >> 1) & 3);
    bf[nf] = *(const f16x8*)(&BhS[col * 32 + cb * 8]);
  }
#pragma unroll
  for (int mf = 0; mf < 4; ++mf)
#pragma unroll
    for (int nf = 0; nf < 4; ++nf)
      acc0[mf][nf] = __builtin_amdgcn_mfma_f32_16x16x32_f16(af[mf], bf[nf], acc0[mf][nf], 0, 0, 0);

  const int pidx = bx * 2 + wc;
#pragma unroll
  for (int mf = 0; mf < 4; ++mf) {
#pragma unroll
    for (int j = 0; j < 4; ++j) {
      const int row = m0 + wr * 64 + mf * 16 + lq * 4 + j;
      const int g0 = 32 + c0[row], g1i = 96 + c1[row], g2i = 224 + c2[row];
      float rowsum = 0.f, rowsq = 0.f;
#pragma unroll
      for (int nf = 0; nf < 4; ++nf) {
        const int col = n0 + wc * 64 + nf * 16 + lr;
        float pre = acc0[mf][nf][j] + bias[col]
                  + W1raw[(size_t)g0 * D1 + col]
                  + W1raw[(size_t)g1i * D1 + col]
                  + W1raw[(size_t)g2i * D1 + col];
        float g = gelu_f(pre);
        Gh[(size_t)row * N + col] = (f16)g;
        rowsum += g; rowsq += g * g;
      }
#pragma unroll
      for (int off = 1; off < 16; off <<= 1) {
        rowsum += __shfl_xor(rowsum, off);
        rowsq  += __shfl_xor(rowsq, off);
      }
      if (lr == 0) {
        part_s[(size_t)row * nparts + pidx] = rowsum;
        part_q[(size_t)row * nparts + pidx] = rowsq;
      }
    }
  }
}

// ---------------- pipelined f16 GEMM (layers 2/3) — round-7 proven schedule ----------------
// FINAL (r20 = r17 exact revert): L2 WM=4 (2 blocks/CU), L3 WM=2, both
// (512,2) — the empirical optimum. r18 (register-capped 6w/EU) spilled;
// r19 (WM=2 L2, 3 blocks/CU) was B-traffic-bound. Occupancy bracketed.
// Loads/tile LD = (WM/2)*(1+ALO) + 1 + BLO; entry wait vmcnt(LD).
// FUSE=true (L3): epilogue emits per-(row, col-block) 19-wide partial logit
// dots (LN3 affine fold) and skips the G3 store entirely.

template <int WM, bool FUSE, bool BLO, bool ALO>
__global__ __launch_bounds__(512, 2)
void gemm_ln(const f16* __restrict__ Ah, const f16* __restrict__ Al,
             const f16* __restrict__ Bh, const f16* __restrict__ Bl,
             int K, int N,
             const float* __restrict__ bias,
             const float* __restrict__ uvec, const float* __restrict__ vvec,
             const float* __restrict__ ps_in, const float* __restrict__ pq_in,
             int np_, float invN,
             float* __restrict__ part_s, float* __restrict__ part_q, int nparts,
             f16* __restrict__ Gh, f16* __restrict__ Gl,
             const float* __restrict__ w4g, float* __restrict__ praw) {
  constexpr int BM = WM * 64;
  constexpr bool USE1 = ALO || BLO;
  __shared__ __align__(16) f16 AhS[3 * BM * 32];
  __shared__ __align__(16) f16 AlS[ALO ? 3 * BM * 32 : 16];
  __shared__ __align__(16) f16 BhS[3 * 128 * 32];
  __shared__ __align__(16) f16 BlS[BLO ? 3 * 128 * 32 : 16];
  __shared__ float mS[BM], rsS[BM];

  const int tid = threadIdx.x;
  const int wave = tid >> 6, lane = tid & 63;
  const int wr = wave >> 1, wc = wave & 1;
  const int lq = lane >> 4, lr = lane & 15;

  const int gx = gridDim.x;
  const int nwg = gx * gridDim.y;
  const int flat = blockIdx.y * gx + blockIdx.x;
  const int cpx = nwg >> 3;
  const int swz = (flat & 7) * cpx + (flat >> 3);
  const int bx = swz % gx, by = swz / gx;
  const int m0 = by * BM, n0 = bx * 128;

  // ---- in-kernel LN stats for this block's rows ----
  for (int r = tid; r < BM; r += 512) {
    const float* pr = ps_in + (size_t)(m0 + r) * np_;
    const float* qr = pq_in + (size_t)(m0 + r) * np_;
    float s = 0.f, q = 0.f;
    for (int pp = 0; pp < np_; pp += 4) {
      float4 a = *(const float4*)(pr + pp);
      float4 b = *(const float4*)(qr + pp);
      s += a.x + a.y + a.z + a.w;
      q += b.x + b.y + b.z + b.w;
    }
    float mean = s * invN;
    mS[r] = mean;
    rsS[r] = 1.0f / sqrtf(q * invN - mean * mean + 1e-5f);
  }

  f32x4 acc0[WM][4], acc1[USE1 ? WM : 1][4];
  const f32x4 vz = {0.f, 0.f, 0.f, 0.f};
#pragma unroll
  for (int a = 0; a < WM; ++a)
#pragma unroll
    for (int b = 0; b < 4; ++b) {
      acc0[a][b] = vz;
      if constexpr (USE1) acc1[a][b] = vz;
    }

  const int nkt = K >> 5;

  auto stage0 = [&](int b, int kt_) {
    const int k0_ = kt_ << 5;
#pragma unroll
    for (int r = 0; r < WM / 2; ++r) {
      int idx = r * 512 + tid, rr = idx >> 2, kq = idx & 3;
      int kqg = kq ^ ((rr >> 1) & 3);
      gl_lds16(&AhS[b * (BM * 32) + idx * 8], Ah + (size_t)(m0 + rr) * K + k0_ + kqg * 8);
    }
    { int rr = tid >> 2, kq = tid & 3, kqg = kq ^ ((rr >> 1) & 3);
      gl_lds16(&BhS[b * (128 * 32) + tid * 8], Bh + (size_t)(n0 + rr) * K + k0_ + kqg * 8); }
  };
  auto stage1 = [&](int b, int kt_) {
    const int k0_ = kt_ << 5;
    if constexpr (ALO) {
#pragma unroll
      for (int r = 0; r < WM / 2; ++r) {
        int idx = r * 512 + tid, rr = idx >> 2, kq = idx & 3;
        int kqg = kq ^ ((rr >> 1) & 3);
        gl_lds16(&AlS[b * (BM * 32) + idx * 8], Al + (size_t)(m0 + rr) * K + k0_ + kqg * 8);
      }
    }
    if constexpr (BLO) {
      int rr = tid >> 2, kq = tid & 3, kqg = kq ^ ((rr >> 1) & 3);
      gl_lds16(&BlS[b * (128 * 32) + tid * 8], Bl + (size_t)(n0 + rr) * K + k0_ + kqg * 8);
    }
  };

  // prologue: tiles 0 and 1 in flight
  stage0(0, 0);
  if constexpr (USE1) stage1(0, 0);
  if (nkt > 1) { stage0(1, 1); if constexpr (USE1) stage1(1, 1); }

  for (int t = 0; t < nkt; ++t) {
    const int cb = t % 3;              // compute buffer
    const int sb = (t + 2) % 3;        // stage target (== buffer of t-1)
    if (t + 1 < nkt) {
      constexpr int LD = (WM / 2) * (1 + (ALO ? 1 : 0)) + 1 + (BLO ? 1 : 0);
      if constexpr (LD >= 6) { WAITV6; }
      else if constexpr (LD == 5) { WAITV5; }
      else if constexpr (LD == 4) { WAITV4; }
      else if constexpr (LD == 3) { WAITV3; }
      else { WAITV2; }
    } else {
      WAITV0;
    }
    BARRIER;

    const bool pf = (t + 2 < nkt);

    f16x8 bf[4], blf[4];
#pragma unroll
    for (int ph = 0; ph < WM / 2; ++ph) {
      const int mfA = ph * 2, mfB = ph * 2 + 1;
      f16x8 aA, aAl, aB, aBl;
      {
        int rowA = wr * (WM * 16) + mfA * 16 + lr;
        int caA = lq ^ ((rowA >> 1) & 3);
        aA = *(const f16x8*)(&AhS[cb * (BM * 32) + rowA * 32 + caA * 8]);
        if constexpr (ALO) aAl = *(const f16x8*)(&AlS[cb * (BM * 32) + rowA * 32 + caA * 8]);
        int rowB = wr * (WM * 16) + mfB * 16 + lr;
        int caB = lq ^ ((rowB >> 1) & 3);
        aB = *(const f16x8*)(&AhS[cb * (BM * 32) + rowB * 32 + caB * 8]);
        if constexpr (ALO) aBl = *(const f16x8*)(&AlS[cb * (BM * 32) + rowB * 32 + caB * 8]);
      }
      if (ph == 0) {
#pragma unroll
        for (int nf = 0; nf < 4; ++nf) {
          int col = wc * 64 + nf * 16 + lr;
          int cc = lq ^ ((col >> 1) & 3);
          bf[nf] = *(const f16x8*)(&BhS[cb * (128 * 32) + col * 32 + cc * 8]);
          if constexpr (BLO)
            blf[nf] = *(const f16x8*)(&BlS[cb * (128 * 32) + col * 32 + cc * 8]);
        }
      }
      if (pf) {
        if (ph == 0) { stage0(sb, t + 2); if (WM == 2) { if constexpr (USE1) stage1(sb, t + 2); } }
        if (ph == 1) { if constexpr (USE1) stage1(sb, t + 2); }
      }
      BARRIER;
      __builtin_amdgcn_s_setprio(1);
#pragma unroll
      for (int nf = 0; nf < 4; ++nf) {
        acc0[mfA][nf] = __builtin_amdgcn_mfma_f32_16x16x32_f16(aA, bf[nf], acc0[mfA][nf], 0, 0, 0);
        if constexpr (BLO)
          acc1[mfA][nf] = __builtin_amdgcn_mfma_f32_16x16x32_f16(aA, blf[nf], acc1[mfA][nf], 0, 0, 0);
        if constexpr (ALO)
          acc1[mfA][nf] = __builtin_amdgcn_mfma_f32_16x16x32_f16(aAl, bf[nf], acc1[mfA][nf], 0, 0, 0);
      }
#pragma unroll
      for (int nf = 0; nf < 4; ++nf) {
        acc0[mfB][nf] = __builtin_amdgcn_mfma_f32_16x16x32_f16(aB, bf[nf], acc0[mfB][nf], 0, 0, 0);
        if constexpr (BLO)
          acc1[mfB][nf] = __builtin_amdgcn_mfma_f32_16x16x32_f16(aB, blf[nf], acc1[mfB][nf], 0, 0, 0);
        if constexpr (ALO)
          acc1[mfB][nf] = __builtin_amdgcn_mfma_f32_16x16x32_f16(aBl, bf[nf], acc1[mfB][nf], 0, 0, 0);
      }
      __builtin_amdgcn_s_setprio(0);
    }
  }

  // ---- epilogue: LN fold + gelu + (store | fused logit partials) ----
  const int pidx = bx * 2 + wc;
#pragma unroll
  for (int mf = 0; mf < WM; ++mf) {
#pragma unroll
    for (int j = 0; j < 4; ++j) {
      const int rl = wr * (WM * 16) + mf * 16 + lq * 4 + j;
      const int row = m0 + rl;
      const float mA = mS[rl], rsA = rsS[rl];
      float gval[4];
      float rowsum = 0.f, rowsq = 0.f;
#pragma unroll
      for (int nf = 0; nf < 4; ++nf) {
        const int col = n0 + wc * 64 + nf * 16 + lr;
        float val = acc0[mf][nf][j];
        if constexpr (USE1) val += acc1[mf][nf][j] * (1.0f / 4096.0f);
        float pre = rsA * val - rsA * mA * uvec[col] + vvec[col] + bias[col];
        float g = gelu_f(pre);
        gval[nf] = g;
        if constexpr (!FUSE) {
          f16 h, l; mk_pair(g, h, l);
          size_t o = (size_t)row * N + col;
          Gh[o] = h;
          if (Gl) Gl[o] = l;
        }
        rowsum += g; rowsq += g * g;
      }
      float lacc[NCLS];
      if constexpr (FUSE) {
#pragma unroll
        for (int c = 0; c < NCLS; ++c) lacc[c] = 0.f;
#pragma unroll
        for (int nf = 0; nf < 4; ++nf) {
          const int col = n0 + wc * 64 + nf * 16 + lr;
          const float* wrow = w4g + (size_t)col * NCLS;
          const float gv = gval[nf];
#pragma unroll
          for (int c = 0; c < NCLS; ++c) lacc[c] += gv * wrow[c];
        }
#pragma unroll
        for (int off = 1; off < 16; off <<= 1) {
#pragma unroll
          for (int c = 0; c < NCLS; ++c) lacc[c] += __shfl_xor(lacc[c], off);
        }
      }
#pragma unroll
      for (int off = 1; off < 16; off <<= 1) {
        rowsum += __shfl_xor(rowsum, off);
        rowsq  += __shfl_xor(rowsq, off);
      }
      if (lr == 0) {
        part_s[(size_t)row * nparts + pidx] = rowsum;
        part_q[(size_t)row * nparts + pidx] = rowsq;
        if constexpr (FUSE) {
          float* pw = praw + ((size_t)row * 16 + pidx) * NCLS;
#pragma unroll
          for (int c = 0; c < NCLS; ++c) pw[c] = lacc[c];
        }
      }
    }
  }
}

// ---------------- head: combine partial dots + LN3 affine + mask + softmax + argmax ----

__global__ __launch_bounds__(256)
void head_kernel(const float* __restrict__ ps3, const float* __restrict__ pq3,
                 const float* __restrict__ praw,
                 const float* __restrict__ u4, const float* __restrict__ v4,
                 const float* __restrict__ b4,
                 const int* __restrict__ pid, const float* __restrict__ amask,
                 float* __restrict__ out_ml, float* __restrict__ out_p,
                 float* __restrict__ out_pred, int rows) {
  const int wave = threadIdx.x >> 6, lane = threadIdx.x & 63;
  const int r = blockIdx.x * 4 + wave;
  if (r >= rows) return;
  const int lp = lane & 15;
  float s = ps3[(size_t)r * 16 + lp];
  float q = pq3[(size_t)r * 16 + lp];
  float acc[NCLS];
  {
    const float* pr = praw + ((size_t)r * 16 + lp) * NCLS;
#pragma unroll
    for (int c = 0; c < NCLS; ++c) acc[c] = pr[c];
  }
#pragma unroll
  for (int off = 1; off < 16; off <<= 1) {
    s += __shfl_xor(s, off);
    q += __shfl_xor(q, off);
#pragma unroll
    for (int c = 0; c < NCLS; ++c) acc[c] += __shfl_xor(acc[c], off);
  }
  const float invN3 = 1.0f / (float)D3;
  const float m = s * invN3;
  const float rs = 1.0f / sqrtf(q * invN3 - m * m + 1e-5f);

  const int p = pid[r];
  float ml[NCLS], mx = -3.4e38f;
#pragma unroll
  for (int c = 0; c < NCLS; ++c) {
    ml[c] = rs * acc[c] - rs * m * u4[c] + v4[c] + b4[c] + amask[(size_t)p * NCLS + c];
    mx = fmaxf(mx, ml[c]);
  }
  float ex[NCLS], ssum = 0.f;
#pragma unroll
  for (int c = 0; c < NCLS; ++c) { ex[c] = expf(ml[c] - mx); ssum += ex[c]; }
  const float inv = 1.0f / ssum;
  float pr2[NCLS];
#pragma unroll
  for (int c = 0; c < NCLS; ++c) pr2[c] = ex[c] * inv;
  int best = 0; float bp = pr2[0];
#pragma unroll
  for (int c = 1; c < NCLS; ++c) { if (pr2[c] > bp) { bp = pr2[c]; best = c; } }
  if (lane < NCLS) {
    out_ml[(size_t)r * NCLS + lane] = ml[lane];
    out_p [(size_t)r * NCLS + lane] = pr2[lane];
  }
  if (lane == 0) out_pred[r] = (float)best;
}

// ---------------- host ----------------

extern "C" void kernel_launch(void* const* d_in, const int* in_sizes, int n_in,
                              void* d_out, int out_size, void* d_ws, size_t ws_size,
                              hipStream_t stream) {
  const float* numeric = (const float*)d_in[0];
  const int*   cat0 = (const int*)d_in[1];
  const int*   cat1 = (const int*)d_in[2];
  const int*   cat2 = (const int*)d_in[3];
  const int*   pid  = (const int*)d_in[4];
  const float* amask= (const float*)d_in[5];
  const float* W1 = (const float*)d_in[6];
  const float* b1 = (const float*)d_in[7];
  const float* g1v= (const float*)d_in[8];
  const float* be1= (const float*)d_in[9];
  const float* W2 = (const float*)d_in[10];
  const float* b2 = (const float*)d_in[11];
  const float* g2v= (const float*)d_in[12];
  const float* be2= (const float*)d_in[13];
  const float* W3 = (const float*)d_in[14];
  const float* b3 = (const float*)d_in[15];
  const float* g3v= (const float*)d_in[16];
  const float* be3= (const float*)d_in[17];
  const float* W4 = (const float*)d_in[18];
  const float* b4 = (const float*)d_in[19];
  (void)in_sizes; (void)n_in; (void)out_size;

  char* p = (char*)d_ws;
  auto alloc = [&](size_t bytes) -> char* {
    char* r = p;
    p += (bytes + 255) & ~(size_t)255;
    return r;
  };

  // fixed workspace
  f16* W1t_h = (f16*)alloc((size_t)D1 * 32 * 2);
  f16* W2t_h = (f16*)alloc((size_t)D2 * D1 * 2);
  f16* W3t_h = (f16*)alloc((size_t)D3 * D2 * 2);
  f16* An_h  = (f16*)alloc((size_t)B_TOT * 32 * 2);
  float* u2  = (float*)alloc((size_t)D2 * 4);
  float* v2  = (float*)alloc((size_t)D2 * 4);
  float* u3  = (float*)alloc((size_t)D3 * 4);
  float* v3  = (float*)alloc((size_t)D3 * 4);
  float* w4g = (float*)alloc((size_t)D3 * NCLS * 4);
  float* u4  = (float*)alloc((size_t)NCLS * 4);
  float* v4  = (float*)alloc((size_t)NCLS * 4);
  float* up_ws = (float*)alloc((size_t)64 * D2 * 4);
  float* vp_ws = (float*)alloc((size_t)64 * D2 * 4);

  size_t fixed = (size_t)(p - (char*)d_ws);
  const size_t per_row = (size_t)D1 * 2 + (size_t)D2 * 2
                       + 2ULL * 64 * 4 + 2ULL * 32 * 4 + 2ULL * 16 * 4;
  int R = B_TOT;
  while (R > 1024 && fixed + (size_t)R * per_row + 4096 > ws_size) R >>= 1;

  f16* G1h = (f16*)alloc((size_t)R * D1 * 2);
  f16* G2h = (f16*)alloc((size_t)R * D2 * 2);
  float* ps1 = (float*)alloc((size_t)R * 64 * 4);
  float* pq1 = (float*)alloc((size_t)R * 64 * 4);
  float* ps2 = (float*)alloc((size_t)R * 32 * 4);
  float* pq2 = (float*)alloc((size_t)R * 32 * 4);
  float* ps3 = (float*)alloc((size_t)R * 16 * 4);
  float* pq3 = (float*)alloc((size_t)R * 16 * 4);
  float* praw = (float*)G1h;  // L3 writes praw after G1 is dead (in-order stream)

  float* out_ml = (float*)d_out;
  float* out_p  = out_ml + (size_t)B_TOT * NCLS;
  float* out_pr = out_p + (size_t)B_TOT * NCLS;

  // ---- prep (once per launch) ----
  hipLaunchKernelGGL(transpose_pair_kernel, dim3(D1 / 64, 1), dim3(256), 0, stream,
                     W1, (const float*)nullptr, (const float*)nullptr,
                     W1t_h, (f16*)nullptr, (float*)nullptr, (float*)nullptr, 32, D1);
  hipLaunchKernelGGL(transpose_pair_kernel, dim3(D2 / 64, D1 / 64), dim3(256), 0, stream,
                     W2, g1v, be1, W2t_h, (f16*)nullptr, up_ws, vp_ws, D1, D2);
  hipLaunchKernelGGL(uv_reduce_kernel, dim3(D2 / 256), dim3(256), 0, stream,
                     up_ws, vp_ws, u2, v2, D2, D1 / 64);
  hipLaunchKernelGGL(transpose_pair_kernel, dim3(D3 / 64, D2 / 64), dim3(256), 0, stream,
                     W3, g2v, be2, W3t_h, (f16*)nullptr, up_ws, vp_ws, D2, D3);
  hipLaunchKernelGGL(uv_reduce_kernel, dim3(D3 / 256), dim3(256), 0, stream,
                     up_ws, vp_ws, u3, v3, D3, D2 / 64);
  hipLaunchKernelGGL(w4g_kernel, dim3((D3 * NCLS + 255) / 256), dim3(256), 0, stream,
                     W4, g3v, w4g);
  hipLaunchKernelGGL(uv4_kernel, dim3(1), dim3(32), 0, stream, W4, g3v, be3, u4, v4);
  hipLaunchKernelGGL(pair_kernel, dim3((B_TOT * 32) / 256), dim3(256), 0, stream,
                     numeric, An_h, B_TOT * 32);

  for (int r0 = 0; r0 < B_TOT; r0 += R) {
    // layer 1: K=32 single-tile f16 GEMM + one-hot gathers
    hipLaunchKernelGGL(gemm1, dim3(D1 / 128, R / 128), dim3(256), 0, stream,
                       An_h + (size_t)r0 * 32, W1t_h, b1,
                       cat0 + r0, cat1 + r0, cat2 + r0, W1,
                       ps1, pq1, 64, G1h);
    // layer 2: plain f16 x f16, WM=4 (BM=256, 74 KB LDS -> 2 blocks/CU)
    hipLaunchKernelGGL((gemm_ln<4, false, false, false>), dim3(D2 / 128, R / 256), dim3(512), 0, stream,
                       G1h, (const f16*)nullptr, W2t_h, (const f16*)nullptr,
                       D1, D2, b2, u2, v2,
                       ps1, pq1, 64, 1.0f / D1,
                       ps2, pq2, 32, G2h, (f16*)nullptr,
                       (const float*)nullptr, (float*)nullptr);
    // layer 3: plain f16 x f16, WM=2, fused head partials -> praw
    hipLaunchKernelGGL((gemm_ln<2, true, false, false>), dim3(D3 / 128, R / 128), dim3(512), 0, stream,
                       G2h, (const f16*)nullptr, W3t_h, (const f16*)nullptr,
                       D2, D3, b3, u3, v3,
                       ps2, pq2, 32, 1.0f / D2,
                       ps3, pq3, 16,
                       (f16*)nullptr, (f16*)nullptr, w4g, praw);
    // head
    hipLaunchKernelGGL(head_kernel, dim3(R / 4), dim3(256), 0, stream,
                       ps3, pq3, praw, u4, v4, b4, pid + r0, amask,
                       out_ml + (size_t)r0 * NCLS, out_p + (size_t)r0 * NCLS,
                       out_pr + r0, R);
  }
}